// Round 7
// baseline (292.780 us; speedup 1.0000x reference)
//
#include <hip/hip_runtime.h>
#include <hip/hip_bf16.h>

typedef short short8 __attribute__((ext_vector_type(8)));
typedef float floatx4 __attribute__((ext_vector_type(4)));
typedef unsigned short ushort;

#define Bb 128
#define Nn 256
#define Hh 150
#define HK 160        // padded col dim for h,c storage
#define Vv 32000
#define NROW 384      // 3 trees * B
#define NINT 64       // internal nodes per tree (0..63)
#define ZROW (Vv + NROW * NINT)   // 56576: zero sentinel row
// proj: frag-native layout. elem(v,seg,col): vb=v>>5, rr=v&31, g=rr>>4,
// q=(rr>>2)&3, rg=rr&3, j=col>>4, m=col&15 ->
//   (vb*10+j)*2048 + seg*512 + g*256 + (q*16+m)*4 + rg

__device__ __forceinline__ float sigf(float x) { return 1.0f / (1.0f + __expf(-x)); }
__device__ __forceinline__ float tanhf_(float x) { return 1.0f - 2.0f / (__expf(2.0f * x) + 1.0f); }
__device__ __forceinline__ float bf2f(ushort s) { union { float f; unsigned u; } v; v.u = ((unsigned)s) << 16; return v.f; }
__device__ __forceinline__ ushort f2bf(float f) { __hip_bfloat16 h = __float2bfloat16(f); return *(ushort*)&h; }

// ---------------- prep: weights -> bf16 B-operand layout + zero sentinel ----
// Wt[640][320] (seg-major cols), Uti[464][160], Utf[160][160], biasw[640]
__global__ __launch_bounds__(256) void k_prep(
    const float* __restrict__ W_iou, const float* __restrict__ W_f,
    const float* __restrict__ U_iou, const float* __restrict__ U_f,
    const float* __restrict__ b_iou, const float* __restrict__ b_f,
    short* __restrict__ Wt, short* __restrict__ Uti, short* __restrict__ Utf,
    float* __restrict__ biasw, ushort* __restrict__ h_u, float* __restrict__ c_u)
{
    int idx = blockIdx.x * 256 + threadIdx.x;
    const int nWt = 640 * 320, nUi = 464 * 160, nUf = 160 * 160;
    if (idx < nWt) {
        int n = idx / 320, k = idx % 320;
        int seg = n / 160, cc = n % 160;
        float v = 0.f;
        if (k < 300 && cc < 150) {
            if (seg == 0)      v = W_iou[k * 450 + cc];
            else if (seg == 1) v = W_iou[k * 450 + 150 + cc];
            else if (seg == 2) v = W_iou[k * 450 + 300 + cc];
            else               v = W_f[k * 150 + cc];
        }
        Wt[idx] = (short)f2bf(v);
    } else if (idx < nWt + nUi) {
        int i2 = idx - nWt; int n = i2 / 160, k = i2 % 160;
        float v = (k < 150 && n < 450) ? U_iou[k * 450 + n] : 0.f;
        Uti[i2] = (short)f2bf(v);
    } else if (idx < nWt + nUi + nUf) {
        int i2 = idx - nWt - nUi; int n = i2 / 160, k = i2 % 160;
        float v = (k < 150) ? U_f[k * 150 + n] : 0.f;
        Utf[i2] = (short)f2bf(v);
    } else if (idx < nWt + nUi + nUf + 640) {
        int n = idx - nWt - nUi - nUf;
        int seg = n / 160, cc = n % 160;
        biasw[n] = (cc < 150) ? (seg < 3 ? b_iou[seg * 150 + cc] : b_f[cc]) : 0.f;
    } else if (idx < nWt + nUi + nUf + 640 + HK) {
        int k = idx - (nWt + nUi + nUf + 640);
        h_u[(long)ZROW * HK + k] = 0;
        c_u[(long)ZROW * HK + k] = 0.f;
    }
}

// ---------------- vocab projection + LEAF fusion via MFMA -------------------
// block = 32 rows; waves split the 10 col-subtiles (j = w, w+4, w+8).
// proj stored frag-native (coalesced 8-B/lane stores). Leaf h/c transposed
// through per-wave LDS -> 16-B coalesced row-major stores.
__global__ __launch_bounds__(256) void k_vproj(
    const float* __restrict__ emb, const short* __restrict__ Wt,
    const float* __restrict__ biasw, ushort* __restrict__ proj,
    ushort* __restrict__ h_u, float* __restrict__ c_u)
{
    __shared__ __align__(16) short As[32 * 328];        // 20992 B
    __shared__ __align__(16) float Tc[4][32][20];       // 10240 B (row stride 80 B)
    __shared__ __align__(16) ushort Th[4][32][24];      // 6144 B (row stride 48 B)
    const int tid = threadIdx.x;
    const int v0 = blockIdx.x * 32;

    for (int i = tid; i < 32 * 80; i += 256) {
        int r = i / 80, q = i % 80, k0 = q * 4;
        short4 sv;
        if (k0 < 300) {
            float4 x = *(const float4*)(emb + (long)(v0 + r) * 300 + k0);
            sv.x = (short)f2bf(x.x); sv.y = (short)f2bf(x.y);
            sv.z = (short)f2bf(x.z); sv.w = (short)f2bf(x.w);
        } else sv = make_short4(0, 0, 0, 0);
        *(short4*)&As[r * 328 + k0] = sv;
    }
    __syncthreads();

    const int w = tid >> 6, lane = tid & 63;
    const int m = lane & 15, quad = lane >> 4, kq = quad * 8;

    short8 a0[10], a1[10];
    #pragma unroll
    for (int ks = 0; ks < 10; ks++) {
        a0[ks] = *(const short8*)&As[m * 328 + kq + ks * 32];
        a1[ks] = *(const short8*)&As[(16 + m) * 328 + kq + ks * 32];
    }

    for (int j = w; j < 10; j += 4) {
        int col = j * 16 + m;
        const short* bp = Wt + (long)col * 320 + kq;
        floatx4 acc[4][2];
        #pragma unroll
        for (int s = 0; s < 4; s++) { acc[s][0] = {0.f,0.f,0.f,0.f}; acc[s][1] = {0.f,0.f,0.f,0.f}; }
        #pragma unroll
        for (int ks = 0; ks < 10; ks++) {
            short8 b0 = *(const short8*)(bp + 0 * 160 * 320 + ks * 32);
            short8 b1 = *(const short8*)(bp + 1 * 160 * 320 + ks * 32);
            short8 b2 = *(const short8*)(bp + 2 * 160 * 320 + ks * 32);
            short8 b3 = *(const short8*)(bp + 3 * 160 * 320 + ks * 32);
            acc[0][0] = __builtin_amdgcn_mfma_f32_16x16x32_bf16(a0[ks], b0, acc[0][0], 0, 0, 0);
            acc[0][1] = __builtin_amdgcn_mfma_f32_16x16x32_bf16(a1[ks], b0, acc[0][1], 0, 0, 0);
            acc[1][0] = __builtin_amdgcn_mfma_f32_16x16x32_bf16(a0[ks], b1, acc[1][0], 0, 0, 0);
            acc[1][1] = __builtin_amdgcn_mfma_f32_16x16x32_bf16(a1[ks], b1, acc[1][1], 0, 0, 0);
            acc[2][0] = __builtin_amdgcn_mfma_f32_16x16x32_bf16(a0[ks], b2, acc[2][0], 0, 0, 0);
            acc[2][1] = __builtin_amdgcn_mfma_f32_16x16x32_bf16(a1[ks], b2, acc[2][1], 0, 0, 0);
            acc[3][0] = __builtin_amdgcn_mfma_f32_16x16x32_bf16(a0[ks], b3, acc[3][0], 0, 0, 0);
            acc[3][1] = __builtin_amdgcn_mfma_f32_16x16x32_bf16(a1[ks], b3, acc[3][1], 0, 0, 0);
        }

        float bias[4] = { biasw[col], biasw[160 + col], biasw[320 + col], biasw[480 + col] };
        float pre[4][2][4];
        #pragma unroll
        for (int s = 0; s < 4; s++)
            #pragma unroll
            for (int g = 0; g < 2; g++)
                #pragma unroll
                for (int reg = 0; reg < 4; reg++)
                    pre[s][g][reg] = acc[s][g][reg] + bias[s];

        // proj: frag-native, one 8-B coalesced store per (seg,g)
        long tbase = (long)(blockIdx.x * 10 + j) * 2048;
        #pragma unroll
        for (int s = 0; s < 4; s++)
            #pragma unroll
            for (int g = 0; g < 2; g++) {
                unsigned u0 = (unsigned)f2bf(pre[s][g][0]) | ((unsigned)f2bf(pre[s][g][1]) << 16);
                unsigned u1 = (unsigned)f2bf(pre[s][g][2]) | ((unsigned)f2bf(pre[s][g][3]) << 16);
                *(uint2*)(proj + tbase + s * 512 + g * 256 + lane * 4) = make_uint2(u0, u1);
            }

        // leaf h/c: compute in-register, transpose via per-wave LDS
        #pragma unroll
        for (int g = 0; g < 2; g++)
            #pragma unroll
            for (int reg = 0; reg < 4; reg++) {
                float iv = sigf(pre[0][g][reg]);
                float ov = sigf(pre[1][g][reg]);
                float uv = tanhf_(pre[2][g][reg]);
                float cc = iv * uv;
                int rr = g * 16 + quad * 4 + reg;
                Tc[w][rr][m] = cc;
                Th[w][rr][m] = f2bf(ov * tanhf_(cc));
            }
        asm volatile("s_waitcnt lgkmcnt(0)" ::: "memory");
        {
            int row = lane >> 1, half = lane & 1;
            int4 hv = *(const int4*)&Th[w][row][half * 8];
            *(int4*)(h_u + (long)(v0 + row) * HK + j * 16 + half * 8) = hv;
            #pragma unroll
            for (int qq = half; qq < 4; qq += 2) {
                float4 cv4 = *(const float4*)&Tc[w][row][qq * 4];
                *(float4*)(c_u + (long)(v0 + row) * HK + j * 16 + qq * 4) = cv4;
            }
        }
        asm volatile("s_waitcnt lgkmcnt(0)" ::: "memory");
    }
}

// ---------------- internal level: fused MFMA + gates, unified state ---------
// grid = nodes*24*G; G splits the 10 col-subtiles across blocks for latency
// hiding on the small levels. Epilogue gathers inline (round-4 structure).
__global__ __launch_bounds__(256) void k_level(
    int t0, int G,
    const int* __restrict__ tq, const int* __restrict__ tp, const int* __restrict__ tn,
    const int* __restrict__ children, const ushort* __restrict__ proj,
    const short* __restrict__ Uti, const short* __restrict__ Utf,
    ushort* __restrict__ h_u, float* __restrict__ c_u)
{
    __shared__ __align__(16) short As[5][16][168];  // seg0=sum, 1..4=children
    __shared__ int idx_s[16][4];
    __shared__ int tok_s[16];

    const int tid = threadIdx.x;
    const int gi = blockIdx.x % G;
    const int rest = blockIdx.x / G;
    const int t = t0 + rest / 24;
    const int r0 = (rest % 24) * 16;

    if (tid < 64) {
        int r = tid >> 2, j = tid & 3;
        int rg = r0 + r, g = rg >> 7, b = rg & 127;
        const int* tok = (g == 0) ? tq : (g == 1 ? tp : tn);
        int ch = children[t * 4 + j];
        int idx;
        if (ch < 0)        idx = ZROW;
        else if (ch >= 64) idx = tok[b * Nn + ch];          // leaf: vocab row
        else               idx = Vv + rg * NINT + ch;       // internal row
        idx_s[r][j] = idx;
        if (j == 0) tok_s[r] = tok[b * Nn + t];
    }
    __syncthreads();

    // stage child h rows (bf16) + bf16 row-sum
    for (int i = tid; i < 16 * 20; i += 256) {
        int r = i / 20, k0 = (i % 20) * 8;
        int4 v0 = *(const int4*)(h_u + (long)idx_s[r][0] * HK + k0);
        int4 v1 = *(const int4*)(h_u + (long)idx_s[r][1] * HK + k0);
        int4 v2 = *(const int4*)(h_u + (long)idx_s[r][2] * HK + k0);
        int4 v3 = *(const int4*)(h_u + (long)idx_s[r][3] * HK + k0);
        *(int4*)&As[1][r][k0] = v0;
        *(int4*)&As[2][r][k0] = v1;
        *(int4*)&As[3][r][k0] = v2;
        *(int4*)&As[4][r][k0] = v3;
        ushort s[8];
        const ushort* p0 = (const ushort*)&v0; const ushort* p1 = (const ushort*)&v1;
        const ushort* p2 = (const ushort*)&v2; const ushort* p3 = (const ushort*)&v3;
        #pragma unroll
        for (int e = 0; e < 8; e++)
            s[e] = f2bf(bf2f(p0[e]) + bf2f(p1[e]) + bf2f(p2[e]) + bf2f(p3[e]));
        *(int4*)&As[0][r][k0] = *(int4*)s;
    }
    __syncthreads();

    const int w = tid >> 6, lane = tid & 63;
    const int m = lane & 15, kq = (lane >> 4) * 8;
    const int rbase = (lane >> 4) * 4;

    for (int nt = gi * 4 + w; nt < 10; nt += 4 * G) {
        int col = nt * 16 + m;
        const short* bi  = Uti + (long)(col) * HK + kq;
        const short* bo  = Uti + (long)(150 + col) * HK + kq;
        const short* bu  = Uti + (long)(300 + col) * HK + kq;
        const short* bff = Utf + (long)col * HK + kq;
        floatx4 ai = {0.f,0.f,0.f,0.f}, ao = ai, au = ai;
        floatx4 af0 = ai, af1 = ai, af2 = ai, af3 = ai;
        #pragma unroll
        for (int ks = 0; ks < 5; ks++) {
            short8 asum = *(const short8*)&As[0][m][kq + ks * 32];
            short8 ac0  = *(const short8*)&As[1][m][kq + ks * 32];
            short8 ac1  = *(const short8*)&As[2][m][kq + ks * 32];
            short8 ac2  = *(const short8*)&As[3][m][kq + ks * 32];
            short8 ac3  = *(const short8*)&As[4][m][kq + ks * 32];
            short8 vbi = *(const short8*)(bi + ks * 32);
            short8 vbo = *(const short8*)(bo + ks * 32);
            short8 vbu = *(const short8*)(bu + ks * 32);
            short8 vbf = *(const short8*)(bff + ks * 32);
            ai  = __builtin_amdgcn_mfma_f32_16x16x32_bf16(asum, vbi, ai, 0, 0, 0);
            ao  = __builtin_amdgcn_mfma_f32_16x16x32_bf16(asum, vbo, ao, 0, 0, 0);
            au  = __builtin_amdgcn_mfma_f32_16x16x32_bf16(asum, vbu, au, 0, 0, 0);
            af0 = __builtin_amdgcn_mfma_f32_16x16x32_bf16(ac0,  vbf, af0, 0, 0, 0);
            af1 = __builtin_amdgcn_mfma_f32_16x16x32_bf16(ac1,  vbf, af1, 0, 0, 0);
            af2 = __builtin_amdgcn_mfma_f32_16x16x32_bf16(ac2,  vbf, af2, 0, 0, 0);
            af3 = __builtin_amdgcn_mfma_f32_16x16x32_bf16(ac3,  vbf, af3, 0, 0, 0);
        }

        if (col < Hh) {
            #pragma unroll
            for (int reg = 0; reg < 4; reg++) {
                int rg = r0 + rbase + reg;
                int v = tok_s[rbase + reg];
                int vb = v >> 5, rr = v & 31;
                const ushort* pb = proj + ((long)(vb * 10 + nt)) * 2048
                                 + (rr >> 4) * 256 + (((rr >> 2) & 3) * 16 + m) * 4 + (rr & 3);
                float iv = sigf(bf2f(pb[0])      + ai[reg]);
                float ov = sigf(bf2f(pb[512])    + ao[reg]);
                float uv = tanhf_(bf2f(pb[1024]) + au[reg]);
                float fpre = bf2f(pb[1536]);
                float cv = iv * uv;
                cv = fmaf(sigf(fpre + af0[reg]), c_u[(long)idx_s[rbase + reg][0] * HK + col], cv);
                cv = fmaf(sigf(fpre + af1[reg]), c_u[(long)idx_s[rbase + reg][1] * HK + col], cv);
                cv = fmaf(sigf(fpre + af2[reg]), c_u[(long)idx_s[rbase + reg][2] * HK + col], cv);
                cv = fmaf(sigf(fpre + af3[reg]), c_u[(long)idx_s[rbase + reg][3] * HK + col], cv);
                long o = (long)(Vv + rg * NINT + t) * HK + col;
                c_u[o] = cv;
                h_u[o] = f2bf(ov * tanhf_(cv));
            }
        } else {
            #pragma unroll
            for (int reg = 0; reg < 4; reg++) {
                long o = (long)(Vv + (r0 + rbase + reg) * NINT + t) * HK + col;
                c_u[o] = 0.f; h_u[o] = 0;
            }
        }
    }
}

// ---------------- cosine + triplet loss ----------------
__global__ __launch_bounds__(64) void k_cos(const float* __restrict__ c_u, float* __restrict__ out)
{
    int b = blockIdx.x, tid = threadIdx.x;
    const float* qc = c_u + (long)(Vv + (0 * Bb + b) * NINT) * HK;
    const float* pc = c_u + (long)(Vv + (1 * Bb + b) * NINT) * HK;
    const float* nc = c_u + (long)(Vv + (2 * Bb + b) * NINT) * HK;
    float qp = 0, qn = 0, qq = 0, pp = 0, nn2 = 0;
    for (int k = tid; k < Hh; k += 64) {
        float qv = qc[k], pv = pc[k], nv = nc[k];
        qp += qv * pv; qn += qv * nv; qq += qv * qv; pp += pv * pv; nn2 += nv * nv;
    }
    #pragma unroll
    for (int off = 32; off > 0; off >>= 1) {
        qp += __shfl_down(qp, off, 64);
        qn += __shfl_down(qn, off, 64);
        qq += __shfl_down(qq, off, 64);
        pp += __shfl_down(pp, off, 64);
        nn2 += __shfl_down(nn2, off, 64);
    }
    if (tid == 0) {
        float a = qp / (sqrtf(qq * pp) + 1e-8f);
        float d = qn / (sqrtf(qq * nn2) + 1e-8f);
        out[b] = fmaxf(0.0f, 1.0f - a + d);
    }
}

extern "C" void kernel_launch(void* const* d_in, const int* in_sizes, int n_in,
                              void* d_out, int out_size, void* d_ws, size_t ws_size,
                              hipStream_t stream)
{
    const int*   tq       = (const int*)d_in[0];
    const int*   tp       = (const int*)d_in[1];
    const int*   tn       = (const int*)d_in[2];
    const int*   children = (const int*)d_in[3];
    const float* emb      = (const float*)d_in[4];
    const float* W_iou    = (const float*)d_in[5];
    const float* U_iou    = (const float*)d_in[6];
    const float* b_iou    = (const float*)d_in[7];
    const float* W_f      = (const float*)d_in[8];
    const float* U_f      = (const float*)d_in[9];
    const float* b_f      = (const float*)d_in[10];
    float* out = (float*)d_out;

    char* ws = (char*)d_ws;
    ushort* proj  = (ushort*)ws;                        // 1000*10*2048*2      = 40,960,000
    ushort* h_u   = (ushort*)(ws + 40960000);           // 56577*160*2          = 18,104,640
    float*  c_u   = (float*)(ws + 59064640);            // 56577*160*4          = 36,209,280
    short*  Wt    = (short*)(ws + 95273920);            // 640*320*2            = 409,600
    short*  Uti   = (short*)(ws + 95683520);            // 464*160*2            = 148,480
    short*  Utf   = (short*)(ws + 95832000);            // 160*160*2            = 51,200
    float*  biasw = (float*)(ws + 95883200);            // 640*4                = 2,560

    k_prep<<<1194, 256, 0, stream>>>(W_iou, W_f, U_iou, U_f, b_iou, b_f,
                                     Wt, Uti, Utf, biasw, h_u, c_u);
    k_vproj<<<Vv / 32, 256, 0, stream>>>(emb, Wt, biasw, proj, h_u, c_u);
    k_level<<<43 * 24 * 1, 256, 0, stream>>>(21, 1, tq, tp, tn, children, proj, Uti, Utf, h_u, c_u);
    k_level<<<16 * 24 * 2, 256, 0, stream>>>(5,  2, tq, tp, tn, children, proj, Uti, Utf, h_u, c_u);
    k_level<<<4 * 24 * 3, 256, 0, stream>>>(1,   3, tq, tp, tn, children, proj, Uti, Utf, h_u, c_u);
    k_level<<<1 * 24 * 3, 256, 0, stream>>>(0,   3, tq, tp, tn, children, proj, Uti, Utf, h_u, c_u);
    k_cos<<<Bb, 64, 0, stream>>>(c_u, out);
}

// Round 8
// 274.192 us; speedup vs baseline: 1.0678x; 1.0678x over previous
//
#include <hip/hip_runtime.h>
#include <hip/hip_bf16.h>

typedef short short8 __attribute__((ext_vector_type(8)));
typedef float floatx4 __attribute__((ext_vector_type(4)));
typedef unsigned short ushort;

#define Bb 128
#define Nn 256
#define Hh 150
#define HK 160        // padded col dim for h,c storage
#define Vv 32000
#define NROW 384      // 3 trees * B
#define PROJC 640     // row-major, 4 segments x 160: i@0, o@160, u@320, f@480
#define NINT 64       // internal nodes per tree (0..63)
#define ZROW (Vv + NROW * NINT)   // 56576: zero sentinel row

__device__ __forceinline__ float sigf(float x) { return 1.0f / (1.0f + __expf(-x)); }
__device__ __forceinline__ float tanhf_(float x) { return 1.0f - 2.0f / (__expf(2.0f * x) + 1.0f); }
__device__ __forceinline__ float bf2f(ushort s) { union { float f; unsigned u; } v; v.u = ((unsigned)s) << 16; return v.f; }
__device__ __forceinline__ ushort f2bf(float f) { __hip_bfloat16 h = __float2bfloat16(f); return *(ushort*)&h; }

// ---------------- prep: weights -> bf16 B-operand layout + zero sentinel ----
__global__ __launch_bounds__(256) void k_prep(
    const float* __restrict__ W_iou, const float* __restrict__ W_f,
    const float* __restrict__ U_iou, const float* __restrict__ U_f,
    const float* __restrict__ b_iou, const float* __restrict__ b_f,
    short* __restrict__ Wt, short* __restrict__ Uti, short* __restrict__ Utf,
    float* __restrict__ biasw, ushort* __restrict__ h_u, float* __restrict__ c_u)
{
    int idx = blockIdx.x * 256 + threadIdx.x;
    const int nWt = 640 * 320, nUi = 464 * 160, nUf = 160 * 160;
    if (idx < nWt) {
        int n = idx / 320, k = idx % 320;
        int seg = n / 160, cc = n % 160;
        float v = 0.f;
        if (k < 300 && cc < 150) {
            if (seg == 0)      v = W_iou[k * 450 + cc];
            else if (seg == 1) v = W_iou[k * 450 + 150 + cc];
            else if (seg == 2) v = W_iou[k * 450 + 300 + cc];
            else               v = W_f[k * 150 + cc];
        }
        Wt[idx] = (short)f2bf(v);
    } else if (idx < nWt + nUi) {
        int i2 = idx - nWt; int n = i2 / 160, k = i2 % 160;
        float v = (k < 150 && n < 450) ? U_iou[k * 450 + n] : 0.f;
        Uti[i2] = (short)f2bf(v);
    } else if (idx < nWt + nUi + nUf) {
        int i2 = idx - nWt - nUi; int n = i2 / 160, k = i2 % 160;
        float v = (k < 150) ? U_f[k * 150 + n] : 0.f;
        Utf[i2] = (short)f2bf(v);
    } else if (idx < nWt + nUi + nUf + 640) {
        int n = idx - nWt - nUi - nUf;
        int seg = n / 160, cc = n % 160;
        biasw[n] = (cc < 150) ? (seg < 3 ? b_iou[seg * 150 + cc] : b_f[cc]) : 0.f;
    } else if (idx < nWt + nUi + nUf + 640 + HK) {
        int k = idx - (nWt + nUi + nUf + 640);
        h_u[(long)ZROW * HK + k] = 0;
        c_u[(long)ZROW * HK + k] = 0.f;
    }
}

// ---------------- vocab projection + LEAF fusion via MFMA -------------------
// block = 32 rows; waves split the 10 col-subtiles. proj stored ROW-MAJOR via
// per-wave LDS transpose -> all stores are 16-B coalesced. Leaf h/c likewise.
// Tp aliases As (A-frags live in registers after the prologue).
__global__ __launch_bounds__(256) void k_vproj(
    const float* __restrict__ emb, const short* __restrict__ Wt,
    const float* __restrict__ biasw, ushort* __restrict__ proj,
    ushort* __restrict__ h_u, float* __restrict__ c_u)
{
    __shared__ __align__(16) short As[32 * 328];        // 20992 B; Tp alias after prologue
    __shared__ __align__(16) float Tc[4][32][20];       // 10240 B
    __shared__ __align__(16) ushort Th[4][32][24];      // 6144 B
    ushort (*Tp)[32][72] = (ushort (*)[32][72])As;      // 4*32*72*2 = 18432 <= 20992

    const int tid = threadIdx.x;
    const int v0 = blockIdx.x * 32;

    for (int i = tid; i < 32 * 80; i += 256) {
        int r = i / 80, q = i % 80, k0 = q * 4;
        short4 sv;
        if (k0 < 300) {
            float4 x = *(const float4*)(emb + (long)(v0 + r) * 300 + k0);
            sv.x = (short)f2bf(x.x); sv.y = (short)f2bf(x.y);
            sv.z = (short)f2bf(x.z); sv.w = (short)f2bf(x.w);
        } else sv = make_short4(0, 0, 0, 0);
        *(short4*)&As[r * 328 + k0] = sv;
    }
    __syncthreads();

    const int w = tid >> 6, lane = tid & 63;
    const int m = lane & 15, quad = lane >> 4, kq = quad * 8;

    short8 a0[10], a1[10];
    #pragma unroll
    for (int ks = 0; ks < 10; ks++) {
        a0[ks] = *(const short8*)&As[m * 328 + kq + ks * 32];
        a1[ks] = *(const short8*)&As[(16 + m) * 328 + kq + ks * 32];
    }
    __syncthreads();   // all waves done reading As before Tp overwrites it

    for (int j = w; j < 10; j += 4) {
        int col = j * 16 + m;
        const short* bp = Wt + (long)col * 320 + kq;
        floatx4 acc[4][2];
        #pragma unroll
        for (int s = 0; s < 4; s++) { acc[s][0] = {0.f,0.f,0.f,0.f}; acc[s][1] = {0.f,0.f,0.f,0.f}; }
        #pragma unroll
        for (int ks = 0; ks < 10; ks++) {
            short8 b0 = *(const short8*)(bp + 0 * 160 * 320 + ks * 32);
            short8 b1 = *(const short8*)(bp + 1 * 160 * 320 + ks * 32);
            short8 b2 = *(const short8*)(bp + 2 * 160 * 320 + ks * 32);
            short8 b3 = *(const short8*)(bp + 3 * 160 * 320 + ks * 32);
            acc[0][0] = __builtin_amdgcn_mfma_f32_16x16x32_bf16(a0[ks], b0, acc[0][0], 0, 0, 0);
            acc[0][1] = __builtin_amdgcn_mfma_f32_16x16x32_bf16(a1[ks], b0, acc[0][1], 0, 0, 0);
            acc[1][0] = __builtin_amdgcn_mfma_f32_16x16x32_bf16(a0[ks], b1, acc[1][0], 0, 0, 0);
            acc[1][1] = __builtin_amdgcn_mfma_f32_16x16x32_bf16(a1[ks], b1, acc[1][1], 0, 0, 0);
            acc[2][0] = __builtin_amdgcn_mfma_f32_16x16x32_bf16(a0[ks], b2, acc[2][0], 0, 0, 0);
            acc[2][1] = __builtin_amdgcn_mfma_f32_16x16x32_bf16(a1[ks], b2, acc[2][1], 0, 0, 0);
            acc[3][0] = __builtin_amdgcn_mfma_f32_16x16x32_bf16(a0[ks], b3, acc[3][0], 0, 0, 0);
            acc[3][1] = __builtin_amdgcn_mfma_f32_16x16x32_bf16(a1[ks], b3, acc[3][1], 0, 0, 0);
        }

        float bias[4] = { biasw[col], biasw[160 + col], biasw[320 + col], biasw[480 + col] };
        float pre[4][2][4];
        #pragma unroll
        for (int s = 0; s < 4; s++)
            #pragma unroll
            for (int g = 0; g < 2; g++)
                #pragma unroll
                for (int reg = 0; reg < 4; reg++)
                    pre[s][g][reg] = acc[s][g][reg] + bias[s];

        // transpose preacts + leaf h/c through per-wave LDS
        #pragma unroll
        for (int g = 0; g < 2; g++)
            #pragma unroll
            for (int reg = 0; reg < 4; reg++) {
                int rr = g * 16 + quad * 4 + reg;
                #pragma unroll
                for (int s = 0; s < 4; s++)
                    Tp[w][rr][s * 16 + m] = f2bf(pre[s][g][reg]);
                float iv = sigf(pre[0][g][reg]);
                float ov = sigf(pre[1][g][reg]);
                float uv = tanhf_(pre[2][g][reg]);
                float cc = iv * uv;
                Tc[w][rr][m] = cc;
                Th[w][rr][m] = f2bf(ov * tanhf_(cc));
            }
        asm volatile("s_waitcnt lgkmcnt(0)" ::: "memory");
        {
            int row = lane >> 1, half = lane & 1;
            long rowv = v0 + row;
            #pragma unroll
            for (int s2 = 0; s2 < 2; s2++) {
                int s = half * 2 + s2;
                int4 p0 = *(const int4*)&Tp[w][row][s * 16];
                int4 p1 = *(const int4*)&Tp[w][row][s * 16 + 8];
                *(int4*)(proj + rowv * PROJC + s * 160 + j * 16)     = p0;
                *(int4*)(proj + rowv * PROJC + s * 160 + j * 16 + 8) = p1;
            }
            int4 hv = *(const int4*)&Th[w][row][half * 8];
            *(int4*)(h_u + rowv * HK + j * 16 + half * 8) = hv;
            #pragma unroll
            for (int qq = half; qq < 4; qq += 2) {
                float4 cv4 = *(const float4*)&Tc[w][row][qq * 4];
                *(float4*)(c_u + rowv * HK + j * 16 + qq * 4) = cv4;
            }
        }
        asm volatile("s_waitcnt lgkmcnt(0)" ::: "memory");
    }
}

// ---------------- internal level: fused MFMA + gates, unified state ---------
// children h staged to As (bf16), children c staged to Cs (fp32, coalesced
// float4 loads in the prologue -> epilogue reads LDS, no scattered c gathers).
__global__ __launch_bounds__(256) void k_level(
    int t0, int G,
    const int* __restrict__ tq, const int* __restrict__ tp, const int* __restrict__ tn,
    const int* __restrict__ children, const ushort* __restrict__ proj,
    const short* __restrict__ Uti, const short* __restrict__ Utf,
    ushort* __restrict__ h_u, float* __restrict__ c_u)
{
    __shared__ __align__(16) short As[5][16][168];   // 26880 B: seg0=sum, 1..4=children
    __shared__ __align__(16) float Cs[4][16][164];   // 41984 B (pad 164: 2-way banks)
    __shared__ int idx_s[16][4];
    __shared__ int tok_s[16];

    const int tid = threadIdx.x;
    const int gi = blockIdx.x % G;
    const int rest = blockIdx.x / G;
    const int t = t0 + rest / 24;
    const int r0 = (rest % 24) * 16;

    if (tid < 64) {
        int r = tid >> 2, j = tid & 3;
        int rg = r0 + r, g = rg >> 7, b = rg & 127;
        const int* tok = (g == 0) ? tq : (g == 1 ? tp : tn);
        int ch = children[t * 4 + j];
        int idx;
        if (ch < 0)        idx = ZROW;
        else if (ch >= 64) idx = tok[b * Nn + ch];          // leaf: vocab row
        else               idx = Vv + rg * NINT + ch;       // internal row
        idx_s[r][j] = idx;
        if (j == 0) tok_s[r] = tok[b * Nn + t];
    }
    __syncthreads();

    // stage child h rows (bf16) + bf16 row-sum
    for (int i = tid; i < 16 * 20; i += 256) {
        int r = i / 20, k0 = (i % 20) * 8;
        int4 v0 = *(const int4*)(h_u + (long)idx_s[r][0] * HK + k0);
        int4 v1 = *(const int4*)(h_u + (long)idx_s[r][1] * HK + k0);
        int4 v2 = *(const int4*)(h_u + (long)idx_s[r][2] * HK + k0);
        int4 v3 = *(const int4*)(h_u + (long)idx_s[r][3] * HK + k0);
        *(int4*)&As[1][r][k0] = v0;
        *(int4*)&As[2][r][k0] = v1;
        *(int4*)&As[3][r][k0] = v2;
        *(int4*)&As[4][r][k0] = v3;
        ushort s[8];
        const ushort* p0 = (const ushort*)&v0; const ushort* p1 = (const ushort*)&v1;
        const ushort* p2 = (const ushort*)&v2; const ushort* p3 = (const ushort*)&v3;
        #pragma unroll
        for (int e = 0; e < 8; e++)
            s[e] = f2bf(bf2f(p0[e]) + bf2f(p1[e]) + bf2f(p2[e]) + bf2f(p3[e]));
        *(int4*)&As[0][r][k0] = *(int4*)s;
    }
    // stage child c rows (fp32, coalesced float4)
    for (int i = tid; i < 16 * 40; i += 256) {
        int r = i / 40, k0 = (i % 40) * 4;
        #pragma unroll
        for (int j = 0; j < 4; j++)
            *(float4*)&Cs[j][r][k0] = *(const float4*)(c_u + (long)idx_s[r][j] * HK + k0);
    }
    __syncthreads();

    const int w = tid >> 6, lane = tid & 63;
    const int m = lane & 15, kq = (lane >> 4) * 8;
    const int rbase = (lane >> 4) * 4;

    for (int nt = gi * 4 + w; nt < 10; nt += 4 * G) {
        int col = nt * 16 + m;
        const short* bi  = Uti + (long)(col) * HK + kq;
        const short* bo  = Uti + (long)(150 + col) * HK + kq;
        const short* bu  = Uti + (long)(300 + col) * HK + kq;
        const short* bff = Utf + (long)col * HK + kq;
        floatx4 ai = {0.f,0.f,0.f,0.f}, ao = ai, au = ai;
        floatx4 af0 = ai, af1 = ai, af2 = ai, af3 = ai;
        #pragma unroll
        for (int ks = 0; ks < 5; ks++) {
            short8 asum = *(const short8*)&As[0][m][kq + ks * 32];
            short8 ac0  = *(const short8*)&As[1][m][kq + ks * 32];
            short8 ac1  = *(const short8*)&As[2][m][kq + ks * 32];
            short8 ac2  = *(const short8*)&As[3][m][kq + ks * 32];
            short8 ac3  = *(const short8*)&As[4][m][kq + ks * 32];
            short8 vbi = *(const short8*)(bi + ks * 32);
            short8 vbo = *(const short8*)(bo + ks * 32);
            short8 vbu = *(const short8*)(bu + ks * 32);
            short8 vbf = *(const short8*)(bff + ks * 32);
            ai  = __builtin_amdgcn_mfma_f32_16x16x32_bf16(asum, vbi, ai, 0, 0, 0);
            ao  = __builtin_amdgcn_mfma_f32_16x16x32_bf16(asum, vbo, ao, 0, 0, 0);
            au  = __builtin_amdgcn_mfma_f32_16x16x32_bf16(asum, vbu, au, 0, 0, 0);
            af0 = __builtin_amdgcn_mfma_f32_16x16x32_bf16(ac0,  vbf, af0, 0, 0, 0);
            af1 = __builtin_amdgcn_mfma_f32_16x16x32_bf16(ac1,  vbf, af1, 0, 0, 0);
            af2 = __builtin_amdgcn_mfma_f32_16x16x32_bf16(ac2,  vbf, af2, 0, 0, 0);
            af3 = __builtin_amdgcn_mfma_f32_16x16x32_bf16(ac3,  vbf, af3, 0, 0, 0);
        }

        if (col < Hh) {
            #pragma unroll
            for (int reg = 0; reg < 4; reg++) {
                int r = rbase + reg, rg = r0 + r;
                const ushort* pr = proj + (long)tok_s[r] * PROJC;
                float iv = sigf(bf2f(pr[col])        + ai[reg]);
                float ov = sigf(bf2f(pr[160 + col])  + ao[reg]);
                float uv = tanhf_(bf2f(pr[320 + col]) + au[reg]);
                float fpre = bf2f(pr[480 + col]);
                float cv = iv * uv;
                cv = fmaf(sigf(fpre + af0[reg]), Cs[0][r][col], cv);
                cv = fmaf(sigf(fpre + af1[reg]), Cs[1][r][col], cv);
                cv = fmaf(sigf(fpre + af2[reg]), Cs[2][r][col], cv);
                cv = fmaf(sigf(fpre + af3[reg]), Cs[3][r][col], cv);
                long o = (long)(Vv + rg * NINT + t) * HK + col;
                c_u[o] = cv;
                h_u[o] = f2bf(ov * tanhf_(cv));
            }
        } else {
            #pragma unroll
            for (int reg = 0; reg < 4; reg++) {
                long o = (long)(Vv + (r0 + rbase + reg) * NINT + t) * HK + col;
                c_u[o] = 0.f; h_u[o] = 0;
            }
        }
    }
}

// ---------------- cosine + triplet loss ----------------
__global__ __launch_bounds__(64) void k_cos(const float* __restrict__ c_u, float* __restrict__ out)
{
    int b = blockIdx.x, tid = threadIdx.x;
    const float* qc = c_u + (long)(Vv + (0 * Bb + b) * NINT) * HK;
    const float* pc = c_u + (long)(Vv + (1 * Bb + b) * NINT) * HK;
    const float* nc = c_u + (long)(Vv + (2 * Bb + b) * NINT) * HK;
    float qp = 0, qn = 0, qq = 0, pp = 0, nn2 = 0;
    for (int k = tid; k < Hh; k += 64) {
        float qv = qc[k], pv = pc[k], nv = nc[k];
        qp += qv * pv; qn += qv * nv; qq += qv * qv; pp += pv * pv; nn2 += nv * nv;
    }
    #pragma unroll
    for (int off = 32; off > 0; off >>= 1) {
        qp += __shfl_down(qp, off, 64);
        qn += __shfl_down(qn, off, 64);
        qq += __shfl_down(qq, off, 64);
        pp += __shfl_down(pp, off, 64);
        nn2 += __shfl_down(nn2, off, 64);
    }
    if (tid == 0) {
        float a = qp / (sqrtf(qq * pp) + 1e-8f);
        float d = qn / (sqrtf(qq * nn2) + 1e-8f);
        out[b] = fmaxf(0.0f, 1.0f - a + d);
    }
}

extern "C" void kernel_launch(void* const* d_in, const int* in_sizes, int n_in,
                              void* d_out, int out_size, void* d_ws, size_t ws_size,
                              hipStream_t stream)
{
    const int*   tq       = (const int*)d_in[0];
    const int*   tp       = (const int*)d_in[1];
    const int*   tn       = (const int*)d_in[2];
    const int*   children = (const int*)d_in[3];
    const float* emb      = (const float*)d_in[4];
    const float* W_iou    = (const float*)d_in[5];
    const float* U_iou    = (const float*)d_in[6];
    const float* b_iou    = (const float*)d_in[7];
    const float* W_f      = (const float*)d_in[8];
    const float* U_f      = (const float*)d_in[9];
    const float* b_f      = (const float*)d_in[10];
    float* out = (float*)d_out;

    char* ws = (char*)d_ws;
    ushort* proj  = (ushort*)ws;                        // 32000*640*2          = 40,960,000
    ushort* h_u   = (ushort*)(ws + 40960000);           // 56577*160*2          = 18,104,640
    float*  c_u   = (float*)(ws + 59064640);            // 56577*160*4          = 36,209,280
    short*  Wt    = (short*)(ws + 95273920);            // 640*320*2            = 409,600
    short*  Uti   = (short*)(ws + 95683520);            // 464*160*2            = 148,480
    short*  Utf   = (short*)(ws + 95832000);            // 160*160*2            = 51,200
    float*  biasw = (float*)(ws + 95883200);            // 640*4                = 2,560

    k_prep<<<1194, 256, 0, stream>>>(W_iou, W_f, U_iou, U_f, b_iou, b_f,
                                     Wt, Uti, Utf, biasw, h_u, c_u);
    k_vproj<<<Vv / 32, 256, 0, stream>>>(emb, Wt, biasw, proj, h_u, c_u);
    k_level<<<43 * 24 * 1, 256, 0, stream>>>(21, 1, tq, tp, tn, children, proj, Uti, Utf, h_u, c_u);
    k_level<<<16 * 24 * 2, 256, 0, stream>>>(5,  2, tq, tp, tn, children, proj, Uti, Utf, h_u, c_u);
    k_level<<<4 * 24 * 3, 256, 0, stream>>>(1,   3, tq, tp, tn, children, proj, Uti, Utf, h_u, c_u);
    k_level<<<1 * 24 * 3, 256, 0, stream>>>(0,   3, tq, tp, tn, children, proj, Uti, Utf, h_u, c_u);
    k_cos<<<Bb, 64, 0, stream>>>(c_u, out);
}